// Round 1
// baseline (999.127 us; speedup 1.0000x reference)
//
#include <hip/hip_runtime.h>

// EncoderDecoderLSTM on MI355X: persistent per-batch-tile kernel.
// Each block owns BT=16 batch rows through all 365 encoder + 7 decoder steps.
// Per step: gates[16b x 256r] = h[16x64] @ W^T[64x256] via mfma_f32_16x16x32_f16,
// f16 hi+lo split (3 MFMAs/product) for ~fp32 accuracy; c-state fp32 in regs;
// h round-trips LDS (C-layout write -> A-layout read), rows padded to 72 f16.

typedef _Float16 f16x8 __attribute__((ext_vector_type(8)));
typedef float    f32x4 __attribute__((ext_vector_type(4)));

static constexpr int T_ENC = 365;
static constexpr int HZ    = 7;
static constexpr int BT    = 16;   // batch tile per block
static constexpr int HPAD  = 72;   // padded f16 row stride (144 B) -> conflict-free b128

__device__ __forceinline__ float sigf(float v) {
  return 1.0f / (1.0f + __expf(-v));
}
__device__ __forceinline__ float tanh_fast(float v) {
  v = fminf(fmaxf(v, -15.0f), 15.0f);
  float e = __expf(2.0f * v);
  return (e - 1.0f) / (e + 1.0f);
}

// acc += (Ahi+Alo)*(Whi+Wlo), dropping lo*lo (~2^-22)
__device__ __forceinline__ f32x4 mm3(f16x8 ahi, f16x8 alo, f16x8 whi, f16x8 wlo, f32x4 acc) {
  acc = __builtin_amdgcn_mfma_f32_16x16x32_f16(ahi, whi, acc, 0, 0, 0);
  acc = __builtin_amdgcn_mfma_f32_16x16x32_f16(ahi, wlo, acc, 0, 0, 0);
  acc = __builtin_amdgcn_mfma_f32_16x16x32_f16(alo, whi, acc, 0, 0, 0);
  return acc;
}

__global__ __launch_bounds__(256, 1)
void lstm_fused(const float* __restrict__ x,
                const float* __restrict__ eWih0, const float* __restrict__ eWhh0,
                const float* __restrict__ eb0,
                const float* __restrict__ eWih1, const float* __restrict__ eWhh1,
                const float* __restrict__ eb1,
                const float* __restrict__ dWih0, const float* __restrict__ dWhh0,
                const float* __restrict__ db0,
                const float* __restrict__ dWih1, const float* __restrict__ dWhh1,
                const float* __restrict__ db1,
                const float* __restrict__ fcW, const float* __restrict__ fcb,
                float* __restrict__ out)
{
  __shared__ __align__(16) float    xs[T_ENC * BT];        // x transposed [t][b]
  __shared__ __align__(16) _Float16 h0hi[BT * HPAD], h0lo[BT * HPAD];
  __shared__ __align__(16) _Float16 h1hi[BT * HPAD], h1lo[BT * HPAD];
  __shared__ __align__(16) float    dins[BT];

  const int tid  = threadIdx.x;
  const int lane = tid & 63;
  const int wv   = tid >> 6;      // wave 0..3
  const int n    = lane & 15;     // tile col (gate) / A-row (batch) index
  const int q    = lane >> 4;     // quad
  const int b0g  = blockIdx.x * BT;

  // Stage x[b][t] -> xs[t][b] (coalesced global read; one-time LDS transpose)
  for (int i = tid; i < T_ENC * BT; i += 256) {
    int b = i / T_ENC;
    int t = i - b * T_ENC;
    xs[t * BT + b] = x[(b0g + b) * T_ENC + t];
  }
  for (int i = tid; i < BT * HPAD; i += 256) {
    h0hi[i] = (_Float16)0.f; h0lo[i] = (_Float16)0.f;
    h1hi[i] = (_Float16)0.f; h1lo[i] = (_Float16)0.f;
  }
  if (tid < BT) dins[tid] = 0.f;
  __syncthreads();

  // Weight B-fragments in registers. Wave w owns N-tiles {w,4+w,8+w,12+w}
  // -> ti is the gate type (i,f,g,o), j-range = [16*wv, 16*wv+16).
  f16x8 W0hi[4][2], W0lo[4][2];   // Whh0
  f16x8 W1hi[4][2], W1lo[4][2];   // Wih1
  f16x8 W2hi[4][2], W2lo[4][2];   // Whh1
  float bias0[4], bias1[4], wih0v[4];

  auto load_weights = [&](const float* Wih0_, const float* Whh0_, const float* b0_,
                          const float* Wih1_, const float* Whh1_, const float* b1_) {
    #pragma unroll
    for (int ti = 0; ti < 4; ++ti) {
      const int r = (ti * 4 + wv) * 16 + n;   // global gate row
      bias0[ti] = b0_[r];
      bias1[ti] = b1_[r];
      wih0v[ti] = Wih0_[r];
      #pragma unroll
      for (int kc = 0; kc < 2; ++kc) {
        // B-frag: lane holds B[k][n] = W[r][k], k = kc*32 + q*8 + j (contiguous in W row)
        const float* p0 = Whh0_ + r * 64 + kc * 32 + q * 8;
        const float* p1 = Wih1_ + r * 64 + kc * 32 + q * 8;
        const float* p2 = Whh1_ + r * 64 + kc * 32 + q * 8;
        #pragma unroll
        for (int j = 0; j < 8; ++j) {
          float v0 = p0[j], v1 = p1[j], v2 = p2[j];
          _Float16 a0 = (_Float16)v0, a1 = (_Float16)v1, a2 = (_Float16)v2;
          W0hi[ti][kc][j] = a0; W0lo[ti][kc][j] = (_Float16)(v0 - (float)a0);
          W1hi[ti][kc][j] = a1; W1lo[ti][kc][j] = (_Float16)(v1 - (float)a1);
          W2hi[ti][kc][j] = a2; W2lo[ti][kc][j] = (_Float16)(v2 - (float)a2);
        }
      }
    }
  };

  load_weights(eWih0, eWhh0, eb0, eWih1, eWhh1, eb1);

  f32x4 c0 = {0.f, 0.f, 0.f, 0.f};
  f32x4 c1 = {0.f, 0.f, 0.f, 0.f};

  // A-frag base pointers: lane reads h[b = n][k-chunk]
  const _Float16* h0hip = h0hi + n * HPAD;
  const _Float16* h0lop = h0lo + n * HPAD;
  const _Float16* h1hip = h1hi + n * HPAD;
  const _Float16* h1lop = h1lo + n * HPAD;
  const int wbase = wv * 16 + n;  // this lane's j column for D-layout writes

  #pragma unroll 1
  for (int t = 0; t < T_ENC; ++t) {
    // Read h0(t-1), h1(t-1) A-frags (h1 read early: its buffer is rewritten later)
    f16x8 a0h0 = *(const f16x8*)(h0hip + q * 8);
    f16x8 a0h1 = *(const f16x8*)(h0hip + 32 + q * 8);
    f16x8 a0l0 = *(const f16x8*)(h0lop + q * 8);
    f16x8 a0l1 = *(const f16x8*)(h0lop + 32 + q * 8);
    f16x8 a1h0 = *(const f16x8*)(h1hip + q * 8);
    f16x8 a1h1 = *(const f16x8*)(h1hip + 32 + q * 8);
    f16x8 a1l0 = *(const f16x8*)(h1lop + q * 8);
    f16x8 a1l1 = *(const f16x8*)(h1lop + 32 + q * 8);
    f32x4 xv   = *(const f32x4*)(xs + t * BT + q * 4);

    // Layer 0 gates: bias + x*Wih0 + h0 @ Whh0^T
    f32x4 g[4];
    #pragma unroll
    for (int ti = 0; ti < 4; ++ti) {
      f32x4 a;
      #pragma unroll
      for (int r = 0; r < 4; ++r) a[r] = xv[r] * wih0v[ti] + bias0[ti];
      a = mm3(a0h0, a0l0, W0hi[ti][0], W0lo[ti][0], a);
      a = mm3(a0h1, a0l1, W0hi[ti][1], W0lo[ti][1], a);
      g[ti] = a;
    }
    __syncthreads();   // all waves done reading h0*,h1* old

    f32x4 h0n;
    #pragma unroll
    for (int r = 0; r < 4; ++r) {
      float c = sigf(g[1][r]) * c0[r] + sigf(g[0][r]) * tanh_fast(g[2][r]);
      c0[r] = c;
      h0n[r] = sigf(g[3][r]) * tanh_fast(c);
    }
    #pragma unroll
    for (int r = 0; r < 4; ++r) {   // D-layout: b = q*4+r, j = wbase
      float v = h0n[r];
      _Float16 hi = (_Float16)v;
      h0hi[(q * 4 + r) * HPAD + wbase] = hi;
      h0lo[(q * 4 + r) * HPAD + wbase] = (_Float16)(v - (float)hi);
    }
    __syncthreads();   // h0(t) visible

    f16x8 b0h0 = *(const f16x8*)(h0hip + q * 8);
    f16x8 b0h1 = *(const f16x8*)(h0hip + 32 + q * 8);
    f16x8 b0l0 = *(const f16x8*)(h0lop + q * 8);
    f16x8 b0l1 = *(const f16x8*)(h0lop + 32 + q * 8);

    // Layer 1 gates: bias + h0(t) @ Wih1^T + h1(t-1) @ Whh1^T
    #pragma unroll
    for (int ti = 0; ti < 4; ++ti) {
      f32x4 a;
      #pragma unroll
      for (int r = 0; r < 4; ++r) a[r] = bias1[ti];
      a = mm3(b0h0, b0l0, W1hi[ti][0], W1lo[ti][0], a);
      a = mm3(b0h1, b0l1, W1hi[ti][1], W1lo[ti][1], a);
      a = mm3(a1h0, a1l0, W2hi[ti][0], W2lo[ti][0], a);
      a = mm3(a1h1, a1l1, W2hi[ti][1], W2lo[ti][1], a);
      g[ti] = a;
    }

    f32x4 h1n;
    #pragma unroll
    for (int r = 0; r < 4; ++r) {
      float c = sigf(g[1][r]) * c1[r] + sigf(g[0][r]) * tanh_fast(g[2][r]);
      c1[r] = c;
      h1n[r] = sigf(g[3][r]) * tanh_fast(c);
    }
    #pragma unroll
    for (int r = 0; r < 4; ++r) {
      float v = h1n[r];
      _Float16 hi = (_Float16)v;
      h1hi[(q * 4 + r) * HPAD + wbase] = hi;
      h1lo[(q * 4 + r) * HPAD + wbase] = (_Float16)(v - (float)hi);
    }
    __syncthreads();   // h1(t) visible for next step
  }

  // ---------------- decoder ----------------
  load_weights(dWih0, dWhh0, db0, dWih1, dWhh1, db1);

  float fcw[16];
  #pragma unroll
  for (int j = 0; j < 16; ++j) fcw[j] = fcW[q * 16 + j];
  const float fcb0 = fcb[0];

  #pragma unroll 1
  for (int hz = 0; hz < HZ; ++hz) {
    f16x8 a0h0 = *(const f16x8*)(h0hip + q * 8);
    f16x8 a0h1 = *(const f16x8*)(h0hip + 32 + q * 8);
    f16x8 a0l0 = *(const f16x8*)(h0lop + q * 8);
    f16x8 a0l1 = *(const f16x8*)(h0lop + 32 + q * 8);
    f16x8 a1h0 = *(const f16x8*)(h1hip + q * 8);
    f16x8 a1h1 = *(const f16x8*)(h1hip + 32 + q * 8);
    f16x8 a1l0 = *(const f16x8*)(h1lop + q * 8);
    f16x8 a1l1 = *(const f16x8*)(h1lop + 32 + q * 8);
    f32x4 dv   = *(const f32x4*)(dins + q * 4);

    f32x4 g[4];
    #pragma unroll
    for (int ti = 0; ti < 4; ++ti) {
      f32x4 a;
      #pragma unroll
      for (int r = 0; r < 4; ++r) a[r] = dv[r] * wih0v[ti] + bias0[ti];
      a = mm3(a0h0, a0l0, W0hi[ti][0], W0lo[ti][0], a);
      a = mm3(a0h1, a0l1, W0hi[ti][1], W0lo[ti][1], a);
      g[ti] = a;
    }
    __syncthreads();

    f32x4 h0n;
    #pragma unroll
    for (int r = 0; r < 4; ++r) {
      float c = sigf(g[1][r]) * c0[r] + sigf(g[0][r]) * tanh_fast(g[2][r]);
      c0[r] = c;
      h0n[r] = sigf(g[3][r]) * tanh_fast(c);
    }
    #pragma unroll
    for (int r = 0; r < 4; ++r) {
      float v = h0n[r];
      _Float16 hi = (_Float16)v;
      h0hi[(q * 4 + r) * HPAD + wbase] = hi;
      h0lo[(q * 4 + r) * HPAD + wbase] = (_Float16)(v - (float)hi);
    }
    __syncthreads();

    f16x8 b0h0 = *(const f16x8*)(h0hip + q * 8);
    f16x8 b0h1 = *(const f16x8*)(h0hip + 32 + q * 8);
    f16x8 b0l0 = *(const f16x8*)(h0lop + q * 8);
    f16x8 b0l1 = *(const f16x8*)(h0lop + 32 + q * 8);

    #pragma unroll
    for (int ti = 0; ti < 4; ++ti) {
      f32x4 a;
      #pragma unroll
      for (int r = 0; r < 4; ++r) a[r] = bias1[ti];
      a = mm3(b0h0, b0l0, W1hi[ti][0], W1lo[ti][0], a);
      a = mm3(b0h1, b0l1, W1hi[ti][1], W1lo[ti][1], a);
      a = mm3(a1h0, a1l0, W2hi[ti][0], W2lo[ti][0], a);
      a = mm3(a1h1, a1l1, W2hi[ti][1], W2lo[ti][1], a);
      g[ti] = a;
    }

    f32x4 h1n;
    #pragma unroll
    for (int r = 0; r < 4; ++r) {
      float c = sigf(g[1][r]) * c1[r] + sigf(g[0][r]) * tanh_fast(g[2][r]);
      c1[r] = c;
      h1n[r] = sigf(g[3][r]) * tanh_fast(c);
    }
    #pragma unroll
    for (int r = 0; r < 4; ++r) {
      float v = h1n[r];
      _Float16 hi = (_Float16)v;
      h1hi[(q * 4 + r) * HPAD + wbase] = hi;
      h1lo[(q * 4 + r) * HPAD + wbase] = (_Float16)(v - (float)hi);
    }
    __syncthreads();   // h1 visible for fc

    // fc: pred[b] = fcW . h1[b] + fcb ; wave 0 only (b = n, j-chunk = q*16..+16)
    if (wv == 0) {
      f16x8 hh0 = *(const f16x8*)(h1hi + n * HPAD + q * 16);
      f16x8 hh1 = *(const f16x8*)(h1hi + n * HPAD + q * 16 + 8);
      f16x8 hl0 = *(const f16x8*)(h1lo + n * HPAD + q * 16);
      f16x8 hl1 = *(const f16x8*)(h1lo + n * HPAD + q * 16 + 8);
      float p = 0.f;
      #pragma unroll
      for (int j = 0; j < 8; ++j) p += fcw[j] * ((float)hh0[j] + (float)hl0[j]);
      #pragma unroll
      for (int j = 0; j < 8; ++j) p += fcw[8 + j] * ((float)hh1[j] + (float)hl1[j]);
      p += __shfl_down(p, 32);
      p += __shfl_down(p, 16);
      if (lane < BT) {
        p += fcb0;
        out[(b0g + lane) * HZ + hz] = p;
        dins[lane] = p;   // next decoder input
      }
    }
    __syncthreads();   // dins visible
  }
}

extern "C" void kernel_launch(void* const* d_in, const int* in_sizes, int n_in,
                              void* d_out, int out_size, void* d_ws, size_t ws_size,
                              hipStream_t stream) {
  (void)in_sizes; (void)n_in; (void)d_ws; (void)ws_size; (void)out_size;
  const float* x     = (const float*)d_in[0];
  const float* eWih0 = (const float*)d_in[1];
  const float* eWhh0 = (const float*)d_in[2];
  const float* eb0   = (const float*)d_in[3];
  const float* eWih1 = (const float*)d_in[4];
  const float* eWhh1 = (const float*)d_in[5];
  const float* eb1   = (const float*)d_in[6];
  const float* dWih0 = (const float*)d_in[7];
  const float* dWhh0 = (const float*)d_in[8];
  const float* db0   = (const float*)d_in[9];
  const float* dWih1 = (const float*)d_in[10];
  const float* dWhh1 = (const float*)d_in[11];
  const float* db1   = (const float*)d_in[12];
  const float* fcW   = (const float*)d_in[13];
  const float* fcb   = (const float*)d_in[14];
  float* out = (float*)d_out;

  dim3 grid(4096 / BT);   // 256 blocks ~ 1/CU
  dim3 block(256);        // 4 waves
  hipLaunchKernelGGL(lstm_fused, grid, block, 0, stream,
                     x, eWih0, eWhh0, eb0, eWih1, eWhh1, eb1,
                     dWih0, dWhh0, db0, dWih1, dWhh1, db1, fcW, fcb, out);
}

// Round 2
// 802.161 us; speedup vs baseline: 1.2455x; 1.2455x over previous
//
#include <hip/hip_runtime.h>

// EncoderDecoderLSTM on MI355X — R2: layer-pipelined persistent kernel.
// 512 threads/block (8 waves): waves 0-3 run layer-0 at slot s, waves 4-7 run
// layer-1 at slot s-1 (layer1(t) needs h0(t), h1(t-1) -> 1-slot pipeline).
// h0/h1 double-buffered in LDS by slot parity -> ONE barrier per slot.
// Per step: gates[16b x 256r] = h[16x64] @ W^T[64x256] via mfma_f32_16x16x32_f16,
// f16 hi+lo split (3 MFMAs/product); c-state fp32 in regs.

typedef _Float16 f16x8 __attribute__((ext_vector_type(8)));
typedef float    f32x4 __attribute__((ext_vector_type(4)));

static constexpr int T_ENC = 365;
static constexpr int HZ    = 7;
static constexpr int BT    = 16;   // batch tile per block
static constexpr int HPAD  = 72;   // padded f16 row stride (144 B)

__device__ __forceinline__ float sigf(float v) {
  return 1.0f / (1.0f + __expf(-v));
}
__device__ __forceinline__ float tanh_fast(float v) {
  v = fminf(fmaxf(v, -15.0f), 15.0f);
  float e = __expf(2.0f * v);
  return (e - 1.0f) / (e + 1.0f);
}

// acc += (Ahi+Alo)*(Whi+Wlo), dropping lo*lo (~2^-22)
__device__ __forceinline__ f32x4 mm3(f16x8 ahi, f16x8 alo, f16x8 whi, f16x8 wlo, f32x4 acc) {
  acc = __builtin_amdgcn_mfma_f32_16x16x32_f16(ahi, whi, acc, 0, 0, 0);
  acc = __builtin_amdgcn_mfma_f32_16x16x32_f16(ahi, wlo, acc, 0, 0, 0);
  acc = __builtin_amdgcn_mfma_f32_16x16x32_f16(alo, whi, acc, 0, 0, 0);
  return acc;
}

__global__ __launch_bounds__(512, 2)
void lstm_fused(const float* __restrict__ x,
                const float* __restrict__ eWih0, const float* __restrict__ eWhh0,
                const float* __restrict__ eb0,
                const float* __restrict__ eWih1, const float* __restrict__ eWhh1,
                const float* __restrict__ eb1,
                const float* __restrict__ dWih0, const float* __restrict__ dWhh0,
                const float* __restrict__ db0,
                const float* __restrict__ dWih1, const float* __restrict__ dWhh1,
                const float* __restrict__ db1,
                const float* __restrict__ fcW, const float* __restrict__ fcb,
                float* __restrict__ out)
{
  __shared__ __align__(16) float    xs[T_ENC * BT];                 // x transposed [t][b]
  __shared__ __align__(16) _Float16 h0hi[2][BT * HPAD], h0lo[2][BT * HPAD];
  __shared__ __align__(16) _Float16 h1hi[2][BT * HPAD], h1lo[2][BT * HPAD];
  __shared__ __align__(16) float    dins[BT];

  const int tid  = threadIdx.x;
  const int lane = tid & 63;
  const int wv   = tid >> 6;        // wave 0..7; 0-3 = layer0 group, 4-7 = layer1 group
  const int wg   = wv & 3;          // index within group
  const int n    = lane & 15;       // tile col (gate row) / A-row (batch) index
  const int q    = lane >> 4;       // quad
  const int b0g  = blockIdx.x * BT;
  const int wbase = wg * 16 + n;    // D-layout j column for h writes

  // Stage x[b][t] -> xs[t][b]
  for (int i = tid; i < T_ENC * BT; i += 512) {
    int b = i / T_ENC;
    int t = i - b * T_ENC;
    xs[t * BT + b] = x[(b0g + b) * T_ENC + t];
  }
  for (int i = tid; i < 2 * BT * HPAD; i += 512) {
    ((_Float16*)h0hi)[i] = (_Float16)0.f; ((_Float16*)h0lo)[i] = (_Float16)0.f;
    ((_Float16*)h1hi)[i] = (_Float16)0.f; ((_Float16*)h1lo)[i] = (_Float16)0.f;
  }
  if (tid < BT) dins[tid] = 0.f;

  // Weight registers (shared pool between groups):
  //   group A (layer0): WA = Whh0 ;               wih0v = Wih0 col, biasv = b0
  //   group B (layer1): WA = Wih1 ; WB = Whh1 ;   biasv = b1
  f16x8 WAhi[4][2], WAlo[4][2], WBhi[4][2], WBlo[4][2];
  float biasv[4], wih0v[4];

  auto splitrow = [&](const float* p, f16x8& hi, f16x8& lo) {
    #pragma unroll
    for (int j = 0; j < 8; ++j) {
      float v = p[j];
      _Float16 h = (_Float16)v;
      hi[j] = h; lo[j] = (_Float16)(v - (float)h);
    }
  };
  auto loadA = [&](const float* Wih0_, const float* Whh0_, const float* b0_) {
    #pragma unroll
    for (int ti = 0; ti < 4; ++ti) {
      const int r = (ti * 4 + wg) * 16 + n;
      biasv[ti] = b0_[r];
      wih0v[ti] = Wih0_[r];
      #pragma unroll
      for (int kc = 0; kc < 2; ++kc)
        splitrow(Whh0_ + r * 64 + kc * 32 + q * 8, WAhi[ti][kc], WAlo[ti][kc]);
    }
  };
  auto loadB = [&](const float* Wih1_, const float* Whh1_, const float* b1_) {
    #pragma unroll
    for (int ti = 0; ti < 4; ++ti) {
      const int r = (ti * 4 + wg) * 16 + n;
      biasv[ti] = b1_[r];
      #pragma unroll
      for (int kc = 0; kc < 2; ++kc) {
        splitrow(Wih1_ + r * 64 + kc * 32 + q * 8, WAhi[ti][kc], WAlo[ti][kc]);
        splitrow(Whh1_ + r * 64 + kc * 32 + q * 8, WBhi[ti][kc], WBlo[ti][kc]);
      }
    }
  };

  if (wv < 4) loadA(eWih0, eWhh0, eb0);
  else        loadB(eWih1, eWhh1, eb1);

  f32x4 cst = {0.f, 0.f, 0.f, 0.f};   // c0 on group A, c1 on group B

  // layer0 step: h_new = lstm(x_in, h_prev) ; gates = bias + x*wih0 + h@WA^T
  auto stepA = [&](const _Float16* Hhi, const _Float16* Hlo,
                   _Float16* Ohi, _Float16* Olo, f32x4 xv) {
    const _Float16* hp = Hhi + n * HPAD;
    const _Float16* lp = Hlo + n * HPAD;
    f16x8 ah0 = *(const f16x8*)(hp + q * 8);
    f16x8 ah1 = *(const f16x8*)(hp + 32 + q * 8);
    f16x8 al0 = *(const f16x8*)(lp + q * 8);
    f16x8 al1 = *(const f16x8*)(lp + 32 + q * 8);
    f32x4 g[4];
    #pragma unroll
    for (int ti = 0; ti < 4; ++ti) {
      f32x4 a;
      #pragma unroll
      for (int r = 0; r < 4; ++r) a[r] = xv[r] * wih0v[ti] + biasv[ti];
      a = mm3(ah0, al0, WAhi[ti][0], WAlo[ti][0], a);
      a = mm3(ah1, al1, WAhi[ti][1], WAlo[ti][1], a);
      g[ti] = a;
    }
    #pragma unroll
    for (int r = 0; r < 4; ++r) {
      float c = sigf(g[1][r]) * cst[r] + sigf(g[0][r]) * tanh_fast(g[2][r]);
      cst[r] = c;
      float h = sigf(g[3][r]) * tanh_fast(c);
      _Float16 hi = (_Float16)h;
      Ohi[(q * 4 + r) * HPAD + wbase] = hi;
      Olo[(q * 4 + r) * HPAD + wbase] = (_Float16)(h - (float)hi);
    }
  };

  // layer1 step: gates = bias + h0@WA^T + h1@WB^T
  auto stepB = [&](const _Float16* H0hi, const _Float16* H0lo,
                   const _Float16* H1hi, const _Float16* H1lo,
                   _Float16* Ohi, _Float16* Olo) {
    const _Float16* p0h = H0hi + n * HPAD;
    const _Float16* p0l = H0lo + n * HPAD;
    const _Float16* p1h = H1hi + n * HPAD;
    const _Float16* p1l = H1lo + n * HPAD;
    f16x8 b0h0 = *(const f16x8*)(p0h + q * 8);
    f16x8 b0h1 = *(const f16x8*)(p0h + 32 + q * 8);
    f16x8 b0l0 = *(const f16x8*)(p0l + q * 8);
    f16x8 b0l1 = *(const f16x8*)(p0l + 32 + q * 8);
    f16x8 a1h0 = *(const f16x8*)(p1h + q * 8);
    f16x8 a1h1 = *(const f16x8*)(p1h + 32 + q * 8);
    f16x8 a1l0 = *(const f16x8*)(p1l + q * 8);
    f16x8 a1l1 = *(const f16x8*)(p1l + 32 + q * 8);
    f32x4 g[4];
    #pragma unroll
    for (int ti = 0; ti < 4; ++ti) {
      f32x4 a;
      #pragma unroll
      for (int r = 0; r < 4; ++r) a[r] = biasv[ti];
      a = mm3(b0h0, b0l0, WAhi[ti][0], WAlo[ti][0], a);
      a = mm3(b0h1, b0l1, WAhi[ti][1], WAlo[ti][1], a);
      a = mm3(a1h0, a1l0, WBhi[ti][0], WBlo[ti][0], a);
      a = mm3(a1h1, a1l1, WBhi[ti][1], WBlo[ti][1], a);
      g[ti] = a;
    }
    #pragma unroll
    for (int r = 0; r < 4; ++r) {
      float c = sigf(g[1][r]) * cst[r] + sigf(g[0][r]) * tanh_fast(g[2][r]);
      cst[r] = c;
      float h = sigf(g[3][r]) * tanh_fast(c);
      _Float16 hi = (_Float16)h;
      Ohi[(q * 4 + r) * HPAD + wbase] = hi;
      Olo[(q * 4 + r) * HPAD + wbase] = (_Float16)(h - (float)hi);
    }
  };

  __syncthreads();

  // ---- encoder: slots s=0..365. A computes h0(s) for s<365; B computes h1(s-1) for s>=1.
  // h0(t) lives in buffer t&1; h1(t) in buffer t&1. One barrier per slot.
  #pragma unroll 1
  for (int s = 0; s <= T_ENC; ++s) {
    if (wv < 4) {
      if (s < T_ENC) {
        const int cur = s & 1, prv = cur ^ 1;
        f32x4 xv = *(const f32x4*)(xs + s * BT + q * 4);
        stepA(h0hi[prv], h0lo[prv], h0hi[cur], h0lo[cur], xv);
      } else {
        loadA(dWih0, dWhh0, db0);   // free overlap: A idle in last slot
      }
    } else {
      if (s >= 1) {
        const int t = s - 1;
        const int w1 = t & 1, r1 = w1 ^ 1;
        stepB(h0hi[t & 1], h0lo[t & 1], h1hi[r1], h1lo[r1], h1hi[w1], h1lo[w1]);
      }
    }
    __syncthreads();
  }

  // ---- decoder ----
  if (wv >= 4) loadB(dWih1, dWhh1, db1);
  float fcw[16];
  #pragma unroll
  for (int j = 0; j < 16; ++j) fcw[j] = fcW[q * 16 + j];
  const float fcb0 = fcb[0];
  // encoder left latest h0 (t=364) and h1 (t=364) in buffer 0.

  #pragma unroll 1
  for (int hz = 0; hz < HZ; ++hz) {
    const int p = hz & 1;           // latest state parity at step entry
    if (wv < 4) {
      f32x4 dv = *(const f32x4*)(dins + q * 4);
      stepA(h0hi[p], h0lo[p], h0hi[1 - p], h0lo[1 - p], dv);
    }
    __syncthreads();
    if (wv >= 4) {
      stepB(h0hi[1 - p], h0lo[1 - p], h1hi[p], h1lo[p], h1hi[1 - p], h1lo[1 - p]);
    }
    __syncthreads();
    if (wv == 0) {
      const _Float16* Hhi = h1hi[1 - p];
      const _Float16* Hlo = h1lo[1 - p];
      f16x8 hh0 = *(const f16x8*)(Hhi + n * HPAD + q * 16);
      f16x8 hh1 = *(const f16x8*)(Hhi + n * HPAD + q * 16 + 8);
      f16x8 hl0 = *(const f16x8*)(Hlo + n * HPAD + q * 16);
      f16x8 hl1 = *(const f16x8*)(Hlo + n * HPAD + q * 16 + 8);
      float pacc = 0.f;
      #pragma unroll
      for (int j = 0; j < 8; ++j) pacc += fcw[j] * ((float)hh0[j] + (float)hl0[j]);
      #pragma unroll
      for (int j = 0; j < 8; ++j) pacc += fcw[8 + j] * ((float)hh1[j] + (float)hl1[j]);
      pacc += __shfl_down(pacc, 32);
      pacc += __shfl_down(pacc, 16);
      if (lane < BT) {
        pacc += fcb0;
        out[(b0g + lane) * HZ + hz] = pacc;
        dins[lane] = pacc;
      }
    }
    __syncthreads();
  }
}

extern "C" void kernel_launch(void* const* d_in, const int* in_sizes, int n_in,
                              void* d_out, int out_size, void* d_ws, size_t ws_size,
                              hipStream_t stream) {
  (void)in_sizes; (void)n_in; (void)d_ws; (void)ws_size; (void)out_size;
  const float* x     = (const float*)d_in[0];
  const float* eWih0 = (const float*)d_in[1];
  const float* eWhh0 = (const float*)d_in[2];
  const float* eb0   = (const float*)d_in[3];
  const float* eWih1 = (const float*)d_in[4];
  const float* eWhh1 = (const float*)d_in[5];
  const float* eb1   = (const float*)d_in[6];
  const float* dWih0 = (const float*)d_in[7];
  const float* dWhh0 = (const float*)d_in[8];
  const float* db0   = (const float*)d_in[9];
  const float* dWih1 = (const float*)d_in[10];
  const float* dWhh1 = (const float*)d_in[11];
  const float* db1   = (const float*)d_in[12];
  const float* fcW   = (const float*)d_in[13];
  const float* fcb   = (const float*)d_in[14];
  float* out = (float*)d_out;

  dim3 grid(4096 / BT);   // 256 blocks = 1/CU
  dim3 block(512);        // 8 waves: 4 layer0 + 4 layer1
  hipLaunchKernelGGL(lstm_fused, grid, block, 0, stream,
                     x, eWih0, eWhh0, eb0, eWih1, eWhh1, eb1,
                     dWih0, dWhh0, db0, dWih1, dWhh1, db1, fcW, fcb, out);
}

// Round 3
// 553.841 us; speedup vs baseline: 1.8040x; 1.4484x over previous
//
#include <hip/hip_runtime.h>

// EncoderDecoderLSTM on MI355X — R3: R2's layer-pipelined structure +
// native-hardware activations (v_exp_f32 / v_rcp_f32 via builtins) replacing
// IEEE f32 division sequences (~20 divs/lane/step = ~700 cyc/wave removed).
// 512 threads/block: waves 0-3 = layer0 at slot s, waves 4-7 = layer1 at s-1.
// One barrier per slot; h0/h1 double-buffered in LDS; c-state fp32 in regs.
// f16 hi+lo split (3 MFMAs/product) keeps ~fp32 accuracy over 372 steps.

typedef _Float16 f16x8 __attribute__((ext_vector_type(8)));
typedef float    f32x4 __attribute__((ext_vector_type(4)));

static constexpr int T_ENC = 365;
static constexpr int HZ    = 7;
static constexpr int BT    = 16;   // batch tile per block
static constexpr int HPAD  = 72;   // padded f16 row stride (144 B)

#if __has_builtin(__builtin_amdgcn_exp2f)
__device__ __forceinline__ float fexp2(float x) { return __builtin_amdgcn_exp2f(x); }
#else
__device__ __forceinline__ float fexp2(float x) { return __exp2f(x); }
#endif
#if __has_builtin(__builtin_amdgcn_rcpf)
__device__ __forceinline__ float frcp(float x) { return __builtin_amdgcn_rcpf(x); }
#else
__device__ __forceinline__ float frcp(float x) { return 1.0f / x; }
#endif

// sigmoid: rcp(1+2^(-x*log2e)). Tails are exact: x<<0 -> exp2=inf -> rcp=0;
// x>>0 -> exp2=0 -> rcp(1)=1. No clamp needed.
__device__ __forceinline__ float sigf(float v) {
  return frcp(1.0f + fexp2(v * -1.442695040888963f));
}
// tanh: (t-1)*rcp(t+1), t=2^(2x*log2e). Clamp +-30 so t stays finite (2^86).
__device__ __forceinline__ float tanh_fast(float v) {
  v = fminf(fmaxf(v, -30.0f), 30.0f);
  float t = fexp2(v * 2.885390081777927f);
  return (t - 1.0f) * frcp(t + 1.0f);
}

// acc += (Ahi+Alo)*(Whi+Wlo), dropping lo*lo (~2^-22)
__device__ __forceinline__ f32x4 mm3(f16x8 ahi, f16x8 alo, f16x8 whi, f16x8 wlo, f32x4 acc) {
  acc = __builtin_amdgcn_mfma_f32_16x16x32_f16(ahi, whi, acc, 0, 0, 0);
  acc = __builtin_amdgcn_mfma_f32_16x16x32_f16(ahi, wlo, acc, 0, 0, 0);
  acc = __builtin_amdgcn_mfma_f32_16x16x32_f16(alo, whi, acc, 0, 0, 0);
  return acc;
}

__global__ __launch_bounds__(512, 2)
void lstm_fused(const float* __restrict__ x,
                const float* __restrict__ eWih0, const float* __restrict__ eWhh0,
                const float* __restrict__ eb0,
                const float* __restrict__ eWih1, const float* __restrict__ eWhh1,
                const float* __restrict__ eb1,
                const float* __restrict__ dWih0, const float* __restrict__ dWhh0,
                const float* __restrict__ db0,
                const float* __restrict__ dWih1, const float* __restrict__ dWhh1,
                const float* __restrict__ db1,
                const float* __restrict__ fcW, const float* __restrict__ fcb,
                float* __restrict__ out)
{
  __shared__ __align__(16) float    xs[T_ENC * BT];                 // x transposed [t][b]
  __shared__ __align__(16) _Float16 h0hi[2][BT * HPAD], h0lo[2][BT * HPAD];
  __shared__ __align__(16) _Float16 h1hi[2][BT * HPAD], h1lo[2][BT * HPAD];
  __shared__ __align__(16) float    dins[BT];

  const int tid  = threadIdx.x;
  const int lane = tid & 63;
  const int wv   = tid >> 6;        // wave 0..7; 0-3 = layer0 group, 4-7 = layer1 group
  const int wg   = wv & 3;          // index within group
  const int n    = lane & 15;       // tile col (gate row) / A-row (batch) index
  const int q    = lane >> 4;       // quad
  const int b0g  = blockIdx.x * BT;
  const int wbase = wg * 16 + n;    // D-layout j column for h writes

  // Stage x[b][t] -> xs[t][b]
  for (int i = tid; i < T_ENC * BT; i += 512) {
    int b = i / T_ENC;
    int t = i - b * T_ENC;
    xs[t * BT + b] = x[(b0g + b) * T_ENC + t];
  }
  for (int i = tid; i < 2 * BT * HPAD; i += 512) {
    ((_Float16*)h0hi)[i] = (_Float16)0.f; ((_Float16*)h0lo)[i] = (_Float16)0.f;
    ((_Float16*)h1hi)[i] = (_Float16)0.f; ((_Float16*)h1lo)[i] = (_Float16)0.f;
  }
  if (tid < BT) dins[tid] = 0.f;

  // Weight registers (shared pool between groups):
  //   group A (layer0): WA = Whh0 ;               wih0v = Wih0 col, biasv = b0
  //   group B (layer1): WA = Wih1 ; WB = Whh1 ;   biasv = b1
  f16x8 WAhi[4][2], WAlo[4][2], WBhi[4][2], WBlo[4][2];
  float biasv[4], wih0v[4];

  auto splitrow = [&](const float* p, f16x8& hi, f16x8& lo) {
    #pragma unroll
    for (int j = 0; j < 8; ++j) {
      float v = p[j];
      _Float16 h = (_Float16)v;
      hi[j] = h; lo[j] = (_Float16)(v - (float)h);
    }
  };
  auto loadA = [&](const float* Wih0_, const float* Whh0_, const float* b0_) {
    #pragma unroll
    for (int ti = 0; ti < 4; ++ti) {
      const int r = (ti * 4 + wg) * 16 + n;
      biasv[ti] = b0_[r];
      wih0v[ti] = Wih0_[r];
      #pragma unroll
      for (int kc = 0; kc < 2; ++kc)
        splitrow(Whh0_ + r * 64 + kc * 32 + q * 8, WAhi[ti][kc], WAlo[ti][kc]);
    }
  };
  auto loadB = [&](const float* Wih1_, const float* Whh1_, const float* b1_) {
    #pragma unroll
    for (int ti = 0; ti < 4; ++ti) {
      const int r = (ti * 4 + wg) * 16 + n;
      biasv[ti] = b1_[r];
      #pragma unroll
      for (int kc = 0; kc < 2; ++kc) {
        splitrow(Wih1_ + r * 64 + kc * 32 + q * 8, WAhi[ti][kc], WAlo[ti][kc]);
        splitrow(Whh1_ + r * 64 + kc * 32 + q * 8, WBhi[ti][kc], WBlo[ti][kc]);
      }
    }
  };

  if (wv < 4) loadA(eWih0, eWhh0, eb0);
  else        loadB(eWih1, eWhh1, eb1);

  f32x4 cst = {0.f, 0.f, 0.f, 0.f};   // c0 on group A, c1 on group B

  // layer0 step: h_new = lstm(x_in, h_prev) ; gates = bias + x*wih0 + h@WA^T
  auto stepA = [&](const _Float16* Hhi, const _Float16* Hlo,
                   _Float16* Ohi, _Float16* Olo, f32x4 xv) {
    const _Float16* hp = Hhi + n * HPAD;
    const _Float16* lp = Hlo + n * HPAD;
    f16x8 ah0 = *(const f16x8*)(hp + q * 8);
    f16x8 ah1 = *(const f16x8*)(hp + 32 + q * 8);
    f16x8 al0 = *(const f16x8*)(lp + q * 8);
    f16x8 al1 = *(const f16x8*)(lp + 32 + q * 8);
    f32x4 g[4];
    #pragma unroll
    for (int ti = 0; ti < 4; ++ti) {
      f32x4 a;
      #pragma unroll
      for (int r = 0; r < 4; ++r) a[r] = xv[r] * wih0v[ti] + biasv[ti];
      a = mm3(ah0, al0, WAhi[ti][0], WAlo[ti][0], a);
      a = mm3(ah1, al1, WAhi[ti][1], WAlo[ti][1], a);
      g[ti] = a;
    }
    #pragma unroll
    for (int r = 0; r < 4; ++r) {
      float c = sigf(g[1][r]) * cst[r] + sigf(g[0][r]) * tanh_fast(g[2][r]);
      cst[r] = c;
      float h = sigf(g[3][r]) * tanh_fast(c);
      _Float16 hi = (_Float16)h;
      Ohi[(q * 4 + r) * HPAD + wbase] = hi;
      Olo[(q * 4 + r) * HPAD + wbase] = (_Float16)(h - (float)hi);
    }
  };

  // layer1 step: gates = bias + h0@WA^T + h1@WB^T
  auto stepB = [&](const _Float16* H0hi, const _Float16* H0lo,
                   const _Float16* H1hi, const _Float16* H1lo,
                   _Float16* Ohi, _Float16* Olo) {
    const _Float16* p0h = H0hi + n * HPAD;
    const _Float16* p0l = H0lo + n * HPAD;
    const _Float16* p1h = H1hi + n * HPAD;
    const _Float16* p1l = H1lo + n * HPAD;
    f16x8 b0h0 = *(const f16x8*)(p0h + q * 8);
    f16x8 b0h1 = *(const f16x8*)(p0h + 32 + q * 8);
    f16x8 b0l0 = *(const f16x8*)(p0l + q * 8);
    f16x8 b0l1 = *(const f16x8*)(p0l + 32 + q * 8);
    f16x8 a1h0 = *(const f16x8*)(p1h + q * 8);
    f16x8 a1h1 = *(const f16x8*)(p1h + 32 + q * 8);
    f16x8 a1l0 = *(const f16x8*)(p1l + q * 8);
    f16x8 a1l1 = *(const f16x8*)(p1l + 32 + q * 8);
    f32x4 g[4];
    #pragma unroll
    for (int ti = 0; ti < 4; ++ti) {
      f32x4 a;
      #pragma unroll
      for (int r = 0; r < 4; ++r) a[r] = biasv[ti];
      a = mm3(b0h0, b0l0, WAhi[ti][0], WAlo[ti][0], a);
      a = mm3(b0h1, b0l1, WAhi[ti][1], WAlo[ti][1], a);
      a = mm3(a1h0, a1l0, WBhi[ti][0], WBlo[ti][0], a);
      a = mm3(a1h1, a1l1, WBhi[ti][1], WBlo[ti][1], a);
      g[ti] = a;
    }
    #pragma unroll
    for (int r = 0; r < 4; ++r) {
      float c = sigf(g[1][r]) * cst[r] + sigf(g[0][r]) * tanh_fast(g[2][r]);
      cst[r] = c;
      float h = sigf(g[3][r]) * tanh_fast(c);
      _Float16 hi = (_Float16)h;
      Ohi[(q * 4 + r) * HPAD + wbase] = hi;
      Olo[(q * 4 + r) * HPAD + wbase] = (_Float16)(h - (float)hi);
    }
  };

  __syncthreads();

  // ---- encoder: slots s=0..365. A computes h0(s) for s<365; B computes h1(s-1) for s>=1.
  // h0(t) lives in buffer t&1; h1(t) in buffer t&1. One barrier per slot.
  #pragma unroll 1
  for (int s = 0; s <= T_ENC; ++s) {
    if (wv < 4) {
      if (s < T_ENC) {
        const int cur = s & 1, prv = cur ^ 1;
        f32x4 xv = *(const f32x4*)(xs + s * BT + q * 4);
        stepA(h0hi[prv], h0lo[prv], h0hi[cur], h0lo[cur], xv);
      } else {
        loadA(dWih0, dWhh0, db0);   // free overlap: A idle in last slot
      }
    } else {
      if (s >= 1) {
        const int t = s - 1;
        const int w1 = t & 1, r1 = w1 ^ 1;
        stepB(h0hi[t & 1], h0lo[t & 1], h1hi[r1], h1lo[r1], h1hi[w1], h1lo[w1]);
      }
    }
    __syncthreads();
  }

  // ---- decoder ----
  if (wv >= 4) loadB(dWih1, dWhh1, db1);
  float fcw[16];
  #pragma unroll
  for (int j = 0; j < 16; ++j) fcw[j] = fcW[q * 16 + j];
  const float fcb0 = fcb[0];
  // encoder left latest h0 (t=364) and h1 (t=364) in buffer 0.

  #pragma unroll 1
  for (int hz = 0; hz < HZ; ++hz) {
    const int p = hz & 1;           // latest state parity at step entry
    if (wv < 4) {
      f32x4 dv = *(const f32x4*)(dins + q * 4);
      stepA(h0hi[p], h0lo[p], h0hi[1 - p], h0lo[1 - p], dv);
    }
    __syncthreads();
    if (wv >= 4) {
      stepB(h0hi[1 - p], h0lo[1 - p], h1hi[p], h1lo[p], h1hi[1 - p], h1lo[1 - p]);
    }
    __syncthreads();
    if (wv == 0) {
      const _Float16* Hhi = h1hi[1 - p];
      const _Float16* Hlo = h1lo[1 - p];
      f16x8 hh0 = *(const f16x8*)(Hhi + n * HPAD + q * 16);
      f16x8 hh1 = *(const f16x8*)(Hhi + n * HPAD + q * 16 + 8);
      f16x8 hl0 = *(const f16x8*)(Hlo + n * HPAD + q * 16);
      f16x8 hl1 = *(const f16x8*)(Hlo + n * HPAD + q * 16 + 8);
      float pacc = 0.f;
      #pragma unroll
      for (int j = 0; j < 8; ++j) pacc += fcw[j] * ((float)hh0[j] + (float)hl0[j]);
      #pragma unroll
      for (int j = 0; j < 8; ++j) pacc += fcw[8 + j] * ((float)hh1[j] + (float)hl1[j]);
      pacc += __shfl_down(pacc, 32);
      pacc += __shfl_down(pacc, 16);
      if (lane < BT) {
        pacc += fcb0;
        out[(b0g + lane) * HZ + hz] = pacc;
        dins[lane] = pacc;
      }
    }
    __syncthreads();
  }
}

extern "C" void kernel_launch(void* const* d_in, const int* in_sizes, int n_in,
                              void* d_out, int out_size, void* d_ws, size_t ws_size,
                              hipStream_t stream) {
  (void)in_sizes; (void)n_in; (void)d_ws; (void)ws_size; (void)out_size;
  const float* x     = (const float*)d_in[0];
  const float* eWih0 = (const float*)d_in[1];
  const float* eWhh0 = (const float*)d_in[2];
  const float* eb0   = (const float*)d_in[3];
  const float* eWih1 = (const float*)d_in[4];
  const float* eWhh1 = (const float*)d_in[5];
  const float* eb1   = (const float*)d_in[6];
  const float* dWih0 = (const float*)d_in[7];
  const float* dWhh0 = (const float*)d_in[8];
  const float* db0   = (const float*)d_in[9];
  const float* dWih1 = (const float*)d_in[10];
  const float* dWhh1 = (const float*)d_in[11];
  const float* db1   = (const float*)d_in[12];
  const float* fcW   = (const float*)d_in[13];
  const float* fcb   = (const float*)d_in[14];
  float* out = (float*)d_out;

  dim3 grid(4096 / BT);   // 256 blocks = 1/CU
  dim3 block(512);        // 8 waves: 4 layer0 + 4 layer1
  hipLaunchKernelGGL(lstm_fused, grid, block, 0, stream,
                     x, eWih0, eWhh0, eb0, eWih1, eWhh1, eb1,
                     dWih0, dWhh0, db0, dWih1, dWhh1, db1, fcW, fcb, out);
}